// Round 4
// baseline (58.157 us; speedup 1.0000x reference)
//
#include <hip/hip_runtime.h>

// RBF interpolation weights:
//   sparse_coords: [B=4, N=256, 3] f32
//   grid_coords:   [M=65536, 3] f32
//   out:           [B, M, N] f32, normalized exp(-d2/(2*sigma^2))
//
// Write-bound: 268 MB out; fill kernel on same device proves ~7.0 TB/s.
// Changes vs R1: MPW 8->16 (amortize per-wave prologue), grid coords loaded
// as vec4 with second-half prefetch overlapping first-half compute, and
// non-temporal vec4 stores (output is write-once, 8x L2 size).
// R3 fix: __builtin_nontemporal_store needs a native clang vector type,
// not HIP_vector_type -> use ext_vector_type(4).

typedef float fx4 __attribute__((ext_vector_type(4)));

constexpr int B_ = 4;
constexpr int N_ = 256;
constexpr int M_ = 65536;
constexpr float INV_2SIG2 = 50.0f;  // 1 / (2 * 0.1^2)
constexpr int MPW = 16;             // m-values per wave (two halves of 8)

__global__ __launch_bounds__(256) void rbf_weights_kernel(
    const float* __restrict__ sparse,  // [B, N, 3]
    const float* __restrict__ grid,    // [M, 3]
    float* __restrict__ out)           // [B, M, N]
{
    const int tid  = threadIdx.x;
    const int lane = tid & 63;
    const int wave = tid >> 6;
    const int b    = blockIdx.y;
    const int m0   = (blockIdx.x * 4 + wave) * MPW;

    // Per-lane sparse points: n = 4*lane + k (contiguous -> vec4 store later).
    const float* sp = sparse + (size_t)b * N_ * 3 + (size_t)lane * 12;
    const fx4 p0 = *(const fx4*)(sp + 0);
    const fx4 p1 = *(const fx4*)(sp + 4);
    const fx4 p2 = *(const fx4*)(sp + 8);

    const float sx[4] = {p0.x, p0.w, p1.z, p2.y};
    const float sy[4] = {p0.y, p1.x, p1.w, p2.z};
    const float sz[4] = {p0.z, p1.y, p2.x, p2.w};
    float s2[4];
#pragma unroll
    for (int j = 0; j < 4; ++j)
        s2[j] = sx[j] * sx[j] + sy[j] * sy[j] + sz[j] * sz[j];

    // Grid coords: 16 m * 3 floats = 48 floats = 12 vec4 (wave-uniform,
    // cache-served broadcast). First 6 feed half 0; last 6 prefetch for half 1.
    const fx4* gq = (const fx4*)(grid + (size_t)m0 * 3);
    fx4 q0 = gq[0], q1 = gq[1], q2 = gq[2], q3 = gq[3], q4 = gq[4], q5 = gq[5];
    fx4 r0 = gq[6], r1 = gq[7], r2 = gq[8], r3 = gq[9], r4 = gq[10], r5 = gq[11];

    float* outb = out + ((size_t)b * M_ + m0) * N_ + (size_t)lane * 4;

#pragma unroll
    for (int h = 0; h < 2; ++h) {
        float ga[24];
        if (h == 0) {
            ga[0]=q0.x; ga[1]=q0.y; ga[2]=q0.z; ga[3]=q0.w;
            ga[4]=q1.x; ga[5]=q1.y; ga[6]=q1.z; ga[7]=q1.w;
            ga[8]=q2.x; ga[9]=q2.y; ga[10]=q2.z; ga[11]=q2.w;
            ga[12]=q3.x; ga[13]=q3.y; ga[14]=q3.z; ga[15]=q3.w;
            ga[16]=q4.x; ga[17]=q4.y; ga[18]=q4.z; ga[19]=q4.w;
            ga[20]=q5.x; ga[21]=q5.y; ga[22]=q5.z; ga[23]=q5.w;
        } else {
            ga[0]=r0.x; ga[1]=r0.y; ga[2]=r0.z; ga[3]=r0.w;
            ga[4]=r1.x; ga[5]=r1.y; ga[6]=r1.z; ga[7]=r1.w;
            ga[8]=r2.x; ga[9]=r2.y; ga[10]=r2.z; ga[11]=r2.w;
            ga[12]=r3.x; ga[13]=r3.y; ga[14]=r3.z; ga[15]=r3.w;
            ga[16]=r4.x; ga[17]=r4.y; ga[18]=r4.z; ga[19]=r4.w;
            ga[20]=r5.x; ga[21]=r5.y; ga[22]=r5.z; ga[23]=r5.w;
        }

#pragma unroll
        for (int mi = 0; mi < 8; ++mi) {
            const float gx = ga[3 * mi + 0];
            const float gy = ga[3 * mi + 1];
            const float gz = ga[3 * mi + 2];
            const float g2 = gx * gx + gy * gy + gz * gz;

            float w[4];
            float lsum = 0.0f;
#pragma unroll
            for (int j = 0; j < 4; ++j) {
                float d2 = g2 + s2[j] - 2.0f * (gx * sx[j] + gy * sy[j] + gz * sz[j]);
                d2 = fmaxf(d2, 0.0f);
                const float e = __expf(-d2 * INV_2SIG2);
                w[j] = e;
                lsum += e;
            }

#pragma unroll
            for (int off = 32; off; off >>= 1) lsum += __shfl_xor(lsum, off);

            const float inv = 1.0f / (lsum + 1e-8f);

            fx4 o4;
            o4.x = w[0] * inv;
            o4.y = w[1] * inv;
            o4.z = w[2] * inv;
            o4.w = w[3] * inv;
            __builtin_nontemporal_store(o4, (fx4*)(outb + (size_t)(h * 8 + mi) * N_));
        }
    }
}

extern "C" void kernel_launch(void* const* d_in, const int* in_sizes, int n_in,
                              void* d_out, int out_size, void* d_ws, size_t ws_size,
                              hipStream_t stream) {
    const float* sparse = (const float*)d_in[0];  // [4, 256, 3]
    const float* grid   = (const float*)d_in[1];  // [65536, 3]
    float* out = (float*)d_out;                   // [4, 65536, 256]

    // Each block: 4 waves * MPW m -> 64 m. Blocks per b = 65536/64 = 1024.
    dim3 grid_dim(M_ / (4 * MPW), B_, 1);
    dim3 block_dim(256, 1, 1);
    rbf_weights_kernel<<<grid_dim, block_dim, 0, stream>>>(sparse, grid, out);
}

// Round 5
// 46.424 us; speedup vs baseline: 1.2527x; 1.2527x over previous
//
#include <hip/hip_runtime.h>

// RBF interpolation weights:
//   sparse_coords: [B=4, N=256, 3] f32
//   grid_coords:   [M=65536, 3] f32
//   out:           [B, M, N] f32, normalized exp(-d2/(2*sigma^2))
//
// Write-bound: 268 MB out. R4 lesson: NT stores + MPW=16 regressed (58 µs);
// revert to the R2 structure (MPW=8, plain float4 stores, 47.3 µs) with two
// free VALU micro-opts:
//   - per-m constants ghx = -2*gx etc., so d2 is a pure FMA chain
//   - exp(-50*d2) computed as exp2(d2 * -50*log2e), clamp via fminf(t, 0)

typedef float fx4 __attribute__((ext_vector_type(4)));

constexpr int B_ = 4;
constexpr int N_ = 256;
constexpr int M_ = 65536;
constexpr int MPW = 8;  // m-values per wave
// -1/(2*sigma^2) * log2(e) = -50 * 1.4426950408889634
constexpr float NEG50_LOG2E = -72.13475204444817f;

__global__ __launch_bounds__(256) void rbf_weights_kernel(
    const float* __restrict__ sparse,  // [B, N, 3]
    const float* __restrict__ grid,    // [M, 3]
    float* __restrict__ out)           // [B, M, N]
{
    const int tid  = threadIdx.x;
    const int lane = tid & 63;
    const int wave = tid >> 6;
    const int b    = blockIdx.y;
    const int m0   = (blockIdx.x * 4 + wave) * MPW;

    // Per-lane sparse points: n = 4*lane + k (contiguous -> float4 store).
    const float* sp = sparse + (size_t)b * N_ * 3 + (size_t)lane * 12;
    const fx4 p0 = *(const fx4*)(sp + 0);
    const fx4 p1 = *(const fx4*)(sp + 4);
    const fx4 p2 = *(const fx4*)(sp + 8);

    const float sx[4] = {p0.x, p0.w, p1.z, p2.y};
    const float sy[4] = {p0.y, p1.x, p1.w, p2.z};
    const float sz[4] = {p0.z, p1.y, p2.x, p2.w};
    float s2[4];
#pragma unroll
    for (int j = 0; j < 4; ++j)
        s2[j] = sx[j] * sx[j] + sy[j] * sy[j] + sz[j] * sz[j];

    // Prefetch this wave's MPW grid points (wave-uniform broadcast loads).
    float gx[MPW], gy[MPW], gz[MPW];
    const float* g = grid + (size_t)m0 * 3;
#pragma unroll
    for (int mi = 0; mi < MPW; ++mi) {
        gx[mi] = g[mi * 3 + 0];
        gy[mi] = g[mi * 3 + 1];
        gz[mi] = g[mi * 3 + 2];
    }

    float* outb = out + ((size_t)b * M_ + m0) * N_ + (size_t)lane * 4;

#pragma unroll
    for (int mi = 0; mi < MPW; ++mi) {
        const float g2  = gx[mi] * gx[mi] + gy[mi] * gy[mi] + gz[mi] * gz[mi];
        const float ghx = -2.0f * gx[mi];
        const float ghy = -2.0f * gy[mi];
        const float ghz = -2.0f * gz[mi];

        float w[4];
        float lsum = 0.0f;
#pragma unroll
        for (int j = 0; j < 4; ++j) {
            // d2 = g2 + s2 - 2*(g.s), as a pure FMA chain
            float d2 = fmaf(ghx, sx[j], fmaf(ghy, sy[j], fmaf(ghz, sz[j], g2 + s2[j])));
            // exp(-50*d2) = exp2(d2 * -50*log2e); clamp d2>=0 <=> t<=0
            const float t = fminf(d2 * NEG50_LOG2E, 0.0f);
            const float e = exp2f(t);
            w[j] = e;
            lsum += e;
        }

        // Wave-wide sum over all 64 lanes (full n-row).
#pragma unroll
        for (int off = 32; off; off >>= 1) lsum += __shfl_xor(lsum, off);

        const float inv = 1.0f / (lsum + 1e-8f);

        fx4 o4;
        o4.x = w[0] * inv;
        o4.y = w[1] * inv;
        o4.z = w[2] * inv;
        o4.w = w[3] * inv;
        *(fx4*)(outb + (size_t)mi * N_) = o4;
    }
}

extern "C" void kernel_launch(void* const* d_in, const int* in_sizes, int n_in,
                              void* d_out, int out_size, void* d_ws, size_t ws_size,
                              hipStream_t stream) {
    const float* sparse = (const float*)d_in[0];  // [4, 256, 3]
    const float* grid   = (const float*)d_in[1];  // [65536, 3]
    float* out = (float*)d_out;                   // [4, 65536, 256]

    dim3 grid_dim(M_ / (4 * MPW), B_, 1);  // 2048 x 4
    dim3 block_dim(256, 1, 1);
    rbf_weights_kernel<<<grid_dim, block_dim, 0, stream>>>(sparse, grid, out);
}